// Round 7
// baseline (589.326 us; speedup 1.0000x reference)
//
#include <hip/hip_runtime.h>

#define N_NODES 100000
#define N_EDGES 20000
#define N_INC   800000
#define TDIM    384
#define HID     128
#define NOFF    800000   // node-ptr offset in merged scan
#define NKEYS   120000
#define EPAD    8        // edge cursor stride (ints) = 32B
#define NPAD    4        // node cursor stride (ints) = 16B

#define WPREP_BLOCKS 24    // 24*4 = 96 B-tiles
#define CNT_BLOCKS   1024
#define PROJ_BLOCKS  1563
#define FILL_BLOCKS  3125  // 3125*256 == N_INC exactly
#define SCAN_BLOCKS  118   // 118*1024 >= 120000; all co-resident (2/CU x 256CU)
#define EAGG_BLOCKS  5000
#define NAGG_BLOCKS  2500

typedef __attribute__((ext_vector_type(8))) short short8;
typedef __attribute__((ext_vector_type(4))) float floatx4;

static __device__ __forceinline__ unsigned short f32_bf16_rne(float f) {
  unsigned int u = __float_as_uint(f);
  unsigned int r = u + 0x7FFFu + ((u >> 16) & 1u);
  return (unsigned short)(r >> 16);
}

// ---- K1: fused W-prep (B hi/lo split) + standalone count (+rank capture) ----
__global__ __launch_bounds__(256) void prep_count_kernel(
    const float* __restrict__ W, unsigned short* __restrict__ Bh,
    unsigned short* __restrict__ Bl,
    const int* __restrict__ node_idx, const int* __restrict__ edge_idx,
    int* __restrict__ ecp, int* __restrict__ ncp,
    int* __restrict__ rank_e, int* __restrict__ rank_n)
{
  const int tid = threadIdx.x;
  if (blockIdx.x < WPREP_BLOCKS) {
    // ---- wprep role: 4 B-tiles per block ----
    int b = blockIdx.x * 4 + (tid >> 6);   // 0..95 = kk*8 + nt
    int lane = tid & 63;
    int kk = b >> 3, nt = b & 7;
    int col = lane & 15, quad = lane >> 4;
    size_t o = ((size_t)b * 64 + lane) * 8;
#pragma unroll
    for (int j = 0; j < 8; ++j) {
      int k = kk * 32 + quad * 8 + j;
      float w = W[(size_t)k * HID + nt * 16 + col];
      unsigned short h = f32_bf16_rne(w);
      float hf = __uint_as_float((unsigned int)h << 16);
      Bh[o + j] = h;
      Bl[o + j] = f32_bf16_rne(w - hf);
    }
    return;
  }
  // ---- count role: padded counters; keep the returned rank ----
  int start = (blockIdx.x - WPREP_BLOCKS) * 256 + tid;
  for (int i = start; i < N_INC; i += CNT_BLOCKS * 256) {
    int ed = edge_idx[i];
    int nd = node_idx[i];
    rank_e[i] = atomicAdd(&ecp[ed * EPAD], 1);
    rank_n[i] = atomicAdd(&ncp[nd * NPAD], 1);
  }
}

// ---- K2: single-pass decoupled-lookback scan over 120000 padded counters ----
static __device__ __forceinline__ int padded_cnt(const int* ecp, const int* ncp, int i) {
  return (i < N_EDGES) ? ecp[i * EPAD] : ncp[(i - N_EDGES) * NPAD];
}

__global__ __launch_bounds__(1024) void scan_lookback(
    const int* __restrict__ ecp, const int* __restrict__ ncp,
    int* __restrict__ ptr, unsigned* __restrict__ status, int n)
{
  __shared__ int s[1024];
  __shared__ int carry_s;
  const int tid = threadIdx.x;
  const int b = blockIdx.x;
  int i = b * 1024 + tid;
  int v = (i < n) ? padded_cnt(ecp, ncp, i) : 0;
  s[tid] = v;
  __syncthreads();
  for (int off = 1; off < 1024; off <<= 1) {
    int add = (tid >= off) ? s[tid - off] : 0;
    __syncthreads();
    s[tid] += add;
    __syncthreads();
  }
  int incl = s[tid];     // local inclusive
  int agg = s[1023];     // block aggregate (totals < 2^21, fits 30 bits)
  if (tid == 0) {
    unsigned pack = (b == 0) ? ((2u << 30) | (unsigned)agg)
                             : ((1u << 30) | (unsigned)agg);
    __hip_atomic_store(&status[b], pack, __ATOMIC_RELEASE, __HIP_MEMORY_SCOPE_AGENT);
  }
  int carry = 0;
  if (b > 0) {
    if (tid == 0) {
      int pb = b - 1;
      for (;;) {
        unsigned st = __hip_atomic_load(&status[pb], __ATOMIC_ACQUIRE,
                                        __HIP_MEMORY_SCOPE_AGENT);
        unsigned state = st >> 30;
        if (state == 0u) continue;                 // predecessor not published yet
        carry += (int)(st & 0x3FFFFFFFu);
        if (state == 2u) break;                    // inclusive found
        --pb;                                      // aggregate: keep looking back
      }
      __hip_atomic_store(&status[b], (2u << 30) | (unsigned)(carry + agg),
                         __ATOMIC_RELEASE, __HIP_MEMORY_SCOPE_AGENT);
      carry_s = carry;
    }
    __syncthreads();
    carry = carry_s;
  }
  if (i < n) ptr[i] = carry + incl - v;            // exclusive
  if (b == SCAN_BLOCKS - 1 && tid == 1023) ptr[n] = carry + incl;  // grand total
}

// ---- K3: fused projection (MFMA bf16x3, R1-exact form) + atomic-free fill ---
// proj blocks first in the grid (start ASAP on CUs); fill blocks overlap under
// proj's 122us shadow. fill: position = ptr[seg] + precomputed rank.
__global__ __launch_bounds__(256) void proj_fill_kernel(
    const float* __restrict__ A, const unsigned short* __restrict__ Bh,
    const unsigned short* __restrict__ Bl, const float* __restrict__ bias,
    unsigned short* __restrict__ Hb, float* __restrict__ gsum0,
    const int* __restrict__ node_idx, const int* __restrict__ edge_idx,
    const int* __restrict__ rank_e, const int* __restrict__ rank_n,
    const int* __restrict__ eptr, const int* __restrict__ nptr,
    int* __restrict__ ecols, int* __restrict__ ncols)
{
  __shared__ unsigned short BhS[512 * 8];   // 8 KB
  __shared__ unsigned short BlS[512 * 8];   // 8 KB
  __shared__ float red[4][HID];             // 2 KB (epilogue colsum)
  const int tid = threadIdx.x;

  if (blockIdx.x >= PROJ_BLOCKS) {
    // ---- fill role ----
    int i = (blockIdx.x - PROJ_BLOCKS) * 256 + tid;   // covers N_INC exactly
    int ed = edge_idx[i];
    int nd = node_idx[i];
    int p = eptr[ed] + rank_e[i];
    int q = nptr[nd] - NOFF + rank_n[i];
    __builtin_nontemporal_store(nd, &ecols[p]);
    __builtin_nontemporal_store(ed, &ncols[q]);
    return;
  }

  // ---- proj role (R1-exact, proven local optimum: VGPR 52, occ 39%) ----
  const int wave = tid >> 6;
  const int lane = tid & 63;
  const int col = lane & 15;
  const int quad = lane >> 4;
  const int m0 = blockIdx.x * 64 + wave * 16;

  floatx4 acc[8];
#pragma unroll
  for (int nt = 0; nt < 8; ++nt) acc[nt] = (floatx4){0.f, 0.f, 0.f, 0.f};

  int r = m0 + col;
  if (r >= N_NODES) r = N_NODES - 1;        // clamp loads; stores guarded
  const float* arow = A + (size_t)r * TDIM + quad * 8;

  float ra[8];
  *(float4*)(&ra[0]) = *(const float4*)(arow);
  *(float4*)(&ra[4]) = *(const float4*)(arow + 4);

  for (int kk = 0; kk < 12; ++kk) {
    short8 sh0 = *(const short8*)(Bh + ((size_t)kk * 512 + tid) * 8);
    short8 sh1 = *(const short8*)(Bh + ((size_t)kk * 512 + tid + 256) * 8);
    short8 sl0 = *(const short8*)(Bl + ((size_t)kk * 512 + tid) * 8);
    short8 sl1 = *(const short8*)(Bl + ((size_t)kk * 512 + tid + 256) * 8);
    __syncthreads();
    *(short8*)(BhS + (size_t)tid * 8) = sh0;
    *(short8*)(BhS + ((size_t)tid + 256) * 8) = sh1;
    *(short8*)(BlS + (size_t)tid * 8) = sl0;
    *(short8*)(BlS + ((size_t)tid + 256) * 8) = sl1;

    float rn[8];
    if (kk < 11) {
      *(float4*)(&rn[0]) = *(const float4*)(arow + (kk + 1) * 32);
      *(float4*)(&rn[4]) = *(const float4*)(arow + (kk + 1) * 32 + 4);
    }

    short8 ah, al;
#pragma unroll
    for (int j = 0; j < 8; ++j) {
      float f = ra[j];
      unsigned short h = f32_bf16_rne(f);
      float hf = __uint_as_float((unsigned int)h << 16);
      ah[j] = (short)h;
      al[j] = (short)f32_bf16_rne(f - hf);
    }
    __syncthreads();

#pragma unroll
    for (int nt = 0; nt < 8; ++nt) {
      short8 bh = *(const short8*)(BhS + ((size_t)nt * 64 + lane) * 8);
      short8 bl = *(const short8*)(BlS + ((size_t)nt * 64 + lane) * 8);
      acc[nt] = __builtin_amdgcn_mfma_f32_16x16x32_bf16(ah, bh, acc[nt], 0, 0, 0);
      acc[nt] = __builtin_amdgcn_mfma_f32_16x16x32_bf16(al, bh, acc[nt], 0, 0, 0);
      acc[nt] = __builtin_amdgcn_mfma_f32_16x16x32_bf16(ah, bl, acc[nt], 0, 0, 0);
    }
#pragma unroll
    for (int j = 0; j < 8; ++j) ra[j] = rn[j];
  }

  // epilogue: +bias, write Hb (bf16), exact fp32 column partials -> gsum0
#pragma unroll
  for (int nt = 0; nt < 8; ++nt) {
    float bv = bias[nt * 16 + col];
    float p = 0.f;
#pragma unroll
    for (int rr = 0; rr < 4; ++rr) {
      int row = m0 + quad * 4 + rr;
      float v = acc[nt][rr] + bv;
      if (row < N_NODES) {
        Hb[(size_t)row * HID + nt * 16 + col] = f32_bf16_rne(v);
        p += v;
      }
    }
    p += __shfl_xor(p, 16, 64);
    p += __shfl_xor(p, 32, 64);
    if (quad == 0) red[wave][nt * 16 + col] = p;
  }
  __syncthreads();
  if (tid < HID) {
    float a = red[0][tid] + red[1][tid] + red[2][tid] + red[3][tid];
    atomicAdd(&gsum0[(blockIdx.x & 7) * HID + tid], a);
  }
}

// ---- fused: edge aggregation (bf16 gather, fp32 acc) + scale hypernet ------
__global__ __launch_bounds__(256) void edge_agg_scale_kernel(
    const unsigned short* __restrict__ Hb, const int* __restrict__ eptr,
    const int* __restrict__ ecols, unsigned short* __restrict__ Eb,
    const float* __restrict__ gsum,
    const float* __restrict__ W1, const float* __restrict__ b1,
    const float* __restrict__ W2, const float* __restrict__ b2,
    float* __restrict__ scale)
{
  if (blockIdx.x >= EAGG_BLOCKS) {
    __shared__ float g[HID], t[HID];
    int c = threadIdx.x;
    if (c < HID) {
      float s = 0.f;
#pragma unroll
      for (int k = 0; k < 8; ++k) s += gsum[k * HID + c];
      g[c] = s * (1.0f / (float)N_NODES);
    }
    __syncthreads();
    if (c < HID) {
      float acc = b1[c];
#pragma unroll 8
      for (int k = 0; k < HID; ++k) acc += g[k] * W1[(size_t)k * HID + c];
      t[c] = fmaxf(acc, 0.f);
    }
    __syncthreads();
    if (c < HID) {
      float acc2 = b2[c];
#pragma unroll 8
      for (int k = 0; k < HID; ++k) acc2 += t[k] * W2[(size_t)k * HID + c];
      scale[c] = acc2;
    }
    return;
  }
  int gw = blockIdx.x * 4 + (threadIdx.x >> 6);
  int lane = threadIdx.x & 63;
  int p0 = eptr[gw], p1 = eptr[gw + 1];
  float ax0 = 0.f, ay0 = 0.f, ax1 = 0.f, ay1 = 0.f;
  float ax2 = 0.f, ay2 = 0.f, ax3 = 0.f, ay3 = 0.f;
  for (int base = p0; base < p1; base += 64) {
    int cnt = min(64, p1 - base);
    int idx = (base + lane < p1) ? ecols[base + lane] : 0;
    int j = 0;
    for (; j + 3 < cnt; j += 4) {
      int n0 = __shfl(idx, j, 64);
      int n1 = __shfl(idx, j + 1, 64);
      int n2 = __shfl(idx, j + 2, 64);
      int n3 = __shfl(idx, j + 3, 64);
      unsigned v0 = *(const unsigned*)(Hb + (size_t)n0 * HID + lane * 2);
      unsigned v1 = *(const unsigned*)(Hb + (size_t)n1 * HID + lane * 2);
      unsigned v2 = *(const unsigned*)(Hb + (size_t)n2 * HID + lane * 2);
      unsigned v3 = *(const unsigned*)(Hb + (size_t)n3 * HID + lane * 2);
      ax0 += __uint_as_float(v0 << 16); ay0 += __uint_as_float(v0 & 0xffff0000u);
      ax1 += __uint_as_float(v1 << 16); ay1 += __uint_as_float(v1 & 0xffff0000u);
      ax2 += __uint_as_float(v2 << 16); ay2 += __uint_as_float(v2 & 0xffff0000u);
      ax3 += __uint_as_float(v3 << 16); ay3 += __uint_as_float(v3 & 0xffff0000u);
    }
    for (; j < cnt; ++j) {
      int n0 = __shfl(idx, j, 64);
      unsigned v0 = *(const unsigned*)(Hb + (size_t)n0 * HID + lane * 2);
      ax0 += __uint_as_float(v0 << 16); ay0 += __uint_as_float(v0 & 0xffff0000u);
    }
  }
  float inv = 1.f / (float)max(p1 - p0, 1);
  float sx = ((ax0 + ax1) + (ax2 + ax3)) * inv;
  float sy = ((ay0 + ay1) + (ay2 + ay3)) * inv;
  unsigned pk = ((unsigned)f32_bf16_rne(sy) << 16) | f32_bf16_rne(sx);
  *(unsigned*)(Eb + (size_t)gw * HID + lane * 2) = pk;
}

// --- node aggregation (bf16 gather) + scale + relu; aux: write Hb + colsum ---
__global__ __launch_bounds__(256) void node_agg_kernel(
    const unsigned short* __restrict__ Eb, const int* __restrict__ nptr,
    const int* __restrict__ ncols, const float* __restrict__ scale,
    unsigned short* __restrict__ Hb, float* __restrict__ H,
    float* __restrict__ gsum, int do_aux)
{
  __shared__ float red[4][HID];
  int wave = threadIdx.x >> 6, lane = threadIdx.x & 63;
  float2 sc = *(const float2*)(scale + lane * 2);
  float csx = 0.f, csy = 0.f;
  for (int gw = blockIdx.x * 4 + wave; gw < N_NODES; gw += NAGG_BLOCKS * 4) {
    int p0 = nptr[gw] - NOFF, p1 = nptr[gw + 1] - NOFF;
    float ax0 = 0.f, ay0 = 0.f, ax1 = 0.f, ay1 = 0.f;
    float ax2 = 0.f, ay2 = 0.f, ax3 = 0.f, ay3 = 0.f;
    for (int base = p0; base < p1; base += 64) {
      int cnt = min(64, p1 - base);
      int idx = (base + lane < p1) ? ncols[base + lane] : 0;
      int j = 0;
      for (; j + 3 < cnt; j += 4) {
        int e0 = __shfl(idx, j, 64);
        int e1 = __shfl(idx, j + 1, 64);
        int e2 = __shfl(idx, j + 2, 64);
        int e3 = __shfl(idx, j + 3, 64);
        unsigned v0 = *(const unsigned*)(Eb + (size_t)e0 * HID + lane * 2);
        unsigned v1 = *(const unsigned*)(Eb + (size_t)e1 * HID + lane * 2);
        unsigned v2 = *(const unsigned*)(Eb + (size_t)e2 * HID + lane * 2);
        unsigned v3 = *(const unsigned*)(Eb + (size_t)e3 * HID + lane * 2);
        ax0 += __uint_as_float(v0 << 16); ay0 += __uint_as_float(v0 & 0xffff0000u);
        ax1 += __uint_as_float(v1 << 16); ay1 += __uint_as_float(v1 & 0xffff0000u);
        ax2 += __uint_as_float(v2 << 16); ay2 += __uint_as_float(v2 & 0xffff0000u);
        ax3 += __uint_as_float(v3 << 16); ay3 += __uint_as_float(v3 & 0xffff0000u);
      }
      for (; j < cnt; ++j) {
        int e0 = __shfl(idx, j, 64);
        unsigned v0 = *(const unsigned*)(Eb + (size_t)e0 * HID + lane * 2);
        ax0 += __uint_as_float(v0 << 16); ay0 += __uint_as_float(v0 & 0xffff0000u);
      }
    }
    float inv = 1.f / (float)max(p1 - p0, 1);
    float ox = fmaxf(((ax0 + ax1) + (ax2 + ax3)) * inv * sc.x, 0.f);
    float oy = fmaxf(((ay0 + ay1) + (ay2 + ay3)) * inv * sc.y, 0.f);
    if (do_aux) {
      unsigned pk = ((unsigned)f32_bf16_rne(oy) << 16) | f32_bf16_rne(ox);
      *(unsigned*)(Hb + (size_t)gw * HID + lane * 2) = pk;
      csx += ox; csy += oy;
    } else {
      *(float2*)(H + (size_t)gw * HID + lane * 2) = make_float2(ox, oy);
    }
  }
  if (do_aux) {
    red[wave][lane * 2] = csx;
    red[wave][lane * 2 + 1] = csy;
    __syncthreads();
    if (threadIdx.x < HID) {
      int c = threadIdx.x;
      float a = red[0][c] + red[1][c] + red[2][c] + red[3][c];
      atomicAdd(&gsum[(blockIdx.x & 7) * HID + c], a);
    }
  }
}

// ---------------- launch ----------------
extern "C" void kernel_launch(void* const* d_in, const int* in_sizes, int n_in,
                              void* d_out, int out_size, void* d_ws, size_t ws_size,
                              hipStream_t stream)
{
  const float* text = (const float*)d_in[0];
  const float* Wp   = (const float*)d_in[1];
  const float* bp   = (const float*)d_in[2];
  const float* W1a  = (const float*)d_in[3];
  const float* b1a  = (const float*)d_in[4];
  const float* W2a  = (const float*)d_in[5];
  const float* b2a  = (const float*)d_in[6];
  const float* W1b  = (const float*)d_in[7];
  const float* b1b  = (const float*)d_in[8];
  const float* W2b  = (const float*)d_in[9];
  const float* b2b  = (const float*)d_in[10];
  const int* node_idx = (const int*)d_in[11];
  const int* edge_idx = (const int*)d_in[12];
  float* H = (float*)d_out;

  // ---- workspace layout (bytes) ----
  char* ws = (char*)d_ws;
  int*      ecp    = (int*)(ws + 0);                       // 20000*EPAD ints
  int*      ncp    = (int*)(ws + 640000);                  // 100000*NPAD ints
  float*    gsum0  = (float*)(ws + 2240000);               // 8*128 floats
  float*    gsum1  = (float*)(ws + 2244096);               // 8*128 floats
  unsigned* status = (unsigned*)(ws + 2248192);            // 118 scan flags (512B pad)
  const size_t zero_bytes = 2248704;
  int*   cptr  = (int*)(ws + 2248704);                     // 120001 ints (eptr||nptr)
  int*   eptr  = cptr;
  int*   nptr  = cptr + N_EDGES;
  int*   ecols = (int*)(ws + 2728712);                     // 800000 ints
  int*   ncols = (int*)(ws + 5928712);                     // 800000 ints
  float* scale0 = (float*)(ws + 9128712);                  // 128
  float* scale1 = (float*)(ws + 9129224);                  // 128
  unsigned short* Eb = (unsigned short*)(ws + 9130000);    // 20000*128 bf16 (5.12 MB)
  unsigned short* Hb = (unsigned short*)(ws + 14250000);   // 100000*128 bf16 -> ends 39.85 MB
  // d_out scratch (51.2 MB, fully overwritten by final node_agg):
  //   ranks 6.4 MB, then B tables (no longer overlay ecols — fill runs ∥ proj)
  int* rank_e = (int*)d_out;                               // 800000 ints
  int* rank_n = rank_e + N_INC;                            // 800000 ints
  unsigned short* Bh = (unsigned short*)((char*)d_out + 6400000);  // 96 KB
  unsigned short* Bl = (unsigned short*)((char*)d_out + 6498304);  // 96 KB

  hipMemsetAsync(ws, 0, zero_bytes, stream);

  // K1: wprep ∥ count(+ranks)
  prep_count_kernel<<<WPREP_BLOCKS + CNT_BLOCKS, 256, 0, stream>>>(
      Wp, Bh, Bl, node_idx, edge_idx, ecp, ncp, rank_e, rank_n);

  // K2: single-pass lookback scan (120000 -> cptr, cptr[120000]=total)
  scan_lookback<<<SCAN_BLOCKS, 1024, 0, stream>>>(ecp, ncp, cptr, status, NKEYS);

  // K3: projection ∥ atomic-free fill
  proj_fill_kernel<<<PROJ_BLOCKS + FILL_BLOCKS, 256, 0, stream>>>(
      text, Bh, Bl, bp, Hb, gsum0, node_idx, edge_idx,
      rank_e, rank_n, eptr, nptr, ecols, ncols);

  // layer 1: edge agg (+scale1 role), node agg (writes Hb, fused colsum2)
  edge_agg_scale_kernel<<<EAGG_BLOCKS + 1, 256, 0, stream>>>(
      Hb, eptr, ecols, Eb, gsum0, W1a, b1a, W2a, b2a, scale0);
  node_agg_kernel<<<NAGG_BLOCKS, 256, 0, stream>>>(
      Eb, nptr, ncols, scale0, Hb, H, gsum1, 1);

  // layer 2: edge agg (+scale2 role), node agg (writes final fp32 H)
  edge_agg_scale_kernel<<<EAGG_BLOCKS + 1, 256, 0, stream>>>(
      Hb, eptr, ecols, Eb, gsum1, W1b, b1b, W2b, b2b, scale1);
  node_agg_kernel<<<NAGG_BLOCKS, 256, 0, stream>>>(
      Eb, nptr, ncols, scale1, Hb, H, gsum1, 0);
}

// Round 8
// 562.372 us; speedup vs baseline: 1.0479x; 1.0479x over previous
//
#include <hip/hip_runtime.h>

#define N_NODES 100000
#define N_EDGES 20000
#define N_INC   800000
#define TDIM    384
#define HID     128
#define NOFF    800000   // node-ptr offset in merged scan
#define NKEYS   120000
#define EPAD    8        // edge cursor stride (ints) = 32B
#define NPAD    4        // node cursor stride (ints) = 16B

#define PROJ_BLOCKS 1563
#define CNT_BLOCKS  512
#define FILLE_BLOCKS 3125  // 3125*256 == N_INC exactly
#define FILLN_BLOCKS 3125
#define SCAN_BLOCKS 118    // 118*1024 >= 120000; all co-resident (2/CU x 256CU)
#define EAGG_BLOCKS 5000
#define NAGG_BLOCKS 2500

typedef __attribute__((ext_vector_type(8))) short short8;
typedef __attribute__((ext_vector_type(4))) float floatx4;

static __device__ __forceinline__ unsigned short f32_bf16_rne(float f) {
  unsigned int u = __float_as_uint(f);
  unsigned int r = u + 0x7FFFu + ((u >> 16) & 1u);
  return (unsigned short)(r >> 16);
}

// ---------------- W prep: split W into hi/lo bf16 in B-fragment order ---------
__global__ __launch_bounds__(64) void wprep_kernel(
    const float* __restrict__ W, unsigned short* __restrict__ Bh,
    unsigned short* __restrict__ Bl)
{
  int b = blockIdx.x;              // 0..95 = kk*8 + nt
  int lane = threadIdx.x;
  int kk = b >> 3, nt = b & 7;
  int col = lane & 15, quad = lane >> 4;
  size_t o = ((size_t)b * 64 + lane) * 8;
#pragma unroll
  for (int j = 0; j < 8; ++j) {
    int k = kk * 32 + quad * 8 + j;
    float w = W[(size_t)k * HID + nt * 16 + col];
    unsigned short h = f32_bf16_rne(w);
    float hf = __uint_as_float((unsigned int)h << 16);
    Bh[o + j] = h;
    Bl[o + j] = f32_bf16_rne(w - hf);
  }
}

// ------ fused: projection (MFMA bf16x3) + count — EXACT R1 form (126us).
// count's ~100us of fabric atomics hides fully under proj's 122us shadow.
__global__ __launch_bounds__(256) void proj_count_kernel(
    const float* __restrict__ A, const unsigned short* __restrict__ Bh,
    const unsigned short* __restrict__ Bl, const float* __restrict__ bias,
    unsigned short* __restrict__ Hb, float* __restrict__ gsum0,
    const int* __restrict__ node_idx, const int* __restrict__ edge_idx,
    int* __restrict__ ecp, int* __restrict__ ncp,
    int* __restrict__ rank_e, int* __restrict__ rank_n)
{
  __shared__ unsigned short BhS[512 * 8];   // 8 KB
  __shared__ unsigned short BlS[512 * 8];   // 8 KB
  __shared__ float red[4][HID];             // 2 KB (epilogue colsum)
  const int tid = threadIdx.x;

  if (blockIdx.x >= PROJ_BLOCKS) {
    // ---- count role: atomics on padded counters; keep the returned rank ----
    int start = (blockIdx.x - PROJ_BLOCKS) * 256 + tid;
    for (int i = start; i < N_INC; i += CNT_BLOCKS * 256) {
      int ed = edge_idx[i];
      int nd = node_idx[i];
      rank_e[i] = atomicAdd(&ecp[ed * EPAD], 1);
      rank_n[i] = atomicAdd(&ncp[nd * NPAD], 1);
    }
    return;
  }

  // ---- proj role (VGPR 52, occ 39% — proven local optimum) ----
  const int wave = tid >> 6;
  const int lane = tid & 63;
  const int col = lane & 15;
  const int quad = lane >> 4;
  const int m0 = blockIdx.x * 64 + wave * 16;

  floatx4 acc[8];
#pragma unroll
  for (int nt = 0; nt < 8; ++nt) acc[nt] = (floatx4){0.f, 0.f, 0.f, 0.f};

  int r = m0 + col;
  if (r >= N_NODES) r = N_NODES - 1;        // clamp loads; stores guarded
  const float* arow = A + (size_t)r * TDIM + quad * 8;

  float ra[8];
  *(float4*)(&ra[0]) = *(const float4*)(arow);
  *(float4*)(&ra[4]) = *(const float4*)(arow + 4);

  for (int kk = 0; kk < 12; ++kk) {
    short8 sh0 = *(const short8*)(Bh + ((size_t)kk * 512 + tid) * 8);
    short8 sh1 = *(const short8*)(Bh + ((size_t)kk * 512 + tid + 256) * 8);
    short8 sl0 = *(const short8*)(Bl + ((size_t)kk * 512 + tid) * 8);
    short8 sl1 = *(const short8*)(Bl + ((size_t)kk * 512 + tid + 256) * 8);
    __syncthreads();
    *(short8*)(BhS + (size_t)tid * 8) = sh0;
    *(short8*)(BhS + ((size_t)tid + 256) * 8) = sh1;
    *(short8*)(BlS + (size_t)tid * 8) = sl0;
    *(short8*)(BlS + ((size_t)tid + 256) * 8) = sl1;

    float rn[8];
    if (kk < 11) {
      *(float4*)(&rn[0]) = *(const float4*)(arow + (kk + 1) * 32);
      *(float4*)(&rn[4]) = *(const float4*)(arow + (kk + 1) * 32 + 4);
    }

    short8 ah, al;
#pragma unroll
    for (int j = 0; j < 8; ++j) {
      float f = ra[j];
      unsigned short h = f32_bf16_rne(f);
      float hf = __uint_as_float((unsigned int)h << 16);
      ah[j] = (short)h;
      al[j] = (short)f32_bf16_rne(f - hf);
    }
    __syncthreads();

#pragma unroll
    for (int nt = 0; nt < 8; ++nt) {
      short8 bh = *(const short8*)(BhS + ((size_t)nt * 64 + lane) * 8);
      short8 bl = *(const short8*)(BlS + ((size_t)nt * 64 + lane) * 8);
      acc[nt] = __builtin_amdgcn_mfma_f32_16x16x32_bf16(ah, bh, acc[nt], 0, 0, 0);
      acc[nt] = __builtin_amdgcn_mfma_f32_16x16x32_bf16(al, bh, acc[nt], 0, 0, 0);
      acc[nt] = __builtin_amdgcn_mfma_f32_16x16x32_bf16(ah, bl, acc[nt], 0, 0, 0);
    }
#pragma unroll
    for (int j = 0; j < 8; ++j) ra[j] = rn[j];
  }

  // epilogue: +bias, write Hb (bf16), exact fp32 column partials -> gsum0
#pragma unroll
  for (int nt = 0; nt < 8; ++nt) {
    float bv = bias[nt * 16 + col];
    float p = 0.f;
#pragma unroll
    for (int rr = 0; rr < 4; ++rr) {
      int row = m0 + quad * 4 + rr;
      float v = acc[nt][rr] + bv;
      if (row < N_NODES) {
        Hb[(size_t)row * HID + nt * 16 + col] = f32_bf16_rne(v);
        p += v;
      }
    }
    p += __shfl_xor(p, 16, 64);
    p += __shfl_xor(p, 32, 64);
    if (quad == 0) red[wave][nt * 16 + col] = p;
  }
  __syncthreads();
  if (tid < HID) {
    float a = red[0][tid] + red[1][tid] + red[2][tid] + red[3][tid];
    atomicAdd(&gsum0[(blockIdx.x & 7) * HID + tid], a);
  }
}

// ---- single-pass decoupled-lookback scan over 120000 padded counters --------
static __device__ __forceinline__ int padded_cnt(const int* ecp, const int* ncp, int i) {
  return (i < N_EDGES) ? ecp[i * EPAD] : ncp[(i - N_EDGES) * NPAD];
}

__global__ __launch_bounds__(1024) void scan_lookback(
    const int* __restrict__ ecp, const int* __restrict__ ncp,
    int* __restrict__ ptr, unsigned* __restrict__ status, int n)
{
  __shared__ int s[1024];
  __shared__ int carry_s;
  const int tid = threadIdx.x;
  const int b = blockIdx.x;
  int i = b * 1024 + tid;
  int v = (i < n) ? padded_cnt(ecp, ncp, i) : 0;
  s[tid] = v;
  __syncthreads();
  for (int off = 1; off < 1024; off <<= 1) {
    int add = (tid >= off) ? s[tid - off] : 0;
    __syncthreads();
    s[tid] += add;
    __syncthreads();
  }
  int incl = s[tid];     // local inclusive
  int agg = s[1023];     // block aggregate (totals < 2^21, fits 30 bits)
  if (tid == 0) {
    unsigned pack = (b == 0) ? ((2u << 30) | (unsigned)agg)
                             : ((1u << 30) | (unsigned)agg);
    __hip_atomic_store(&status[b], pack, __ATOMIC_RELEASE, __HIP_MEMORY_SCOPE_AGENT);
  }
  int carry = 0;
  if (b > 0) {
    if (tid == 0) {
      int pb = b - 1;
      for (;;) {
        unsigned st = __hip_atomic_load(&status[pb], __ATOMIC_ACQUIRE,
                                        __HIP_MEMORY_SCOPE_AGENT);
        unsigned state = st >> 30;
        if (state == 0u) continue;
        carry += (int)(st & 0x3FFFFFFFu);
        if (state == 2u) break;
        --pb;
      }
      __hip_atomic_store(&status[b], (2u << 30) | (unsigned)(carry + agg),
                         __ATOMIC_RELEASE, __HIP_MEMORY_SCOPE_AGENT);
      carry_s = carry;
    }
    __syncthreads();
    carry = carry_s;
  }
  if (i < n) ptr[i] = carry + incl - v;            // exclusive
  if (b == SCAN_BLOCKS - 1 && tid == 1023) ptr[n] = carry + incl;
}

// ---------- atomic-free fill, EDGE side only: pos = eptr[ed] + rank ----------
__global__ __launch_bounds__(256) void fill_e_kernel(
    const int* __restrict__ node_idx, const int* __restrict__ edge_idx,
    const int* __restrict__ rank_e, const int* __restrict__ eptr,
    int* __restrict__ ecols)
{
  int i = blockIdx.x * 256 + threadIdx.x;   // grid covers N_INC exactly
  int ed = edge_idx[i];
  int nd = node_idx[i];
  int p = eptr[ed] + rank_e[i];
  __builtin_nontemporal_store(nd, &ecols[p]);
}

// ---- fused: edge aggregation + scale hypernet + (layer1 only) node-fill -----
// fill_n blocks hide under eagg's ~85us gather; nagg (next kernel) consumes
// ncols, so completion by kernel end is sufficient.
__global__ __launch_bounds__(256) void edge_agg_scale_kernel(
    const unsigned short* __restrict__ Hb, const int* __restrict__ eptr,
    const int* __restrict__ ecols, unsigned short* __restrict__ Eb,
    const float* __restrict__ gsum,
    const float* __restrict__ W1, const float* __restrict__ b1,
    const float* __restrict__ W2, const float* __restrict__ b2,
    float* __restrict__ scale,
    const int* __restrict__ node_idx, const int* __restrict__ edge_idx,
    const int* __restrict__ rank_n, const int* __restrict__ nptr,
    int* __restrict__ ncols)
{
  if (blockIdx.x > EAGG_BLOCKS) {
    // ---- fill_n role (present only in the layer-1 launch) ----
    int i = (blockIdx.x - EAGG_BLOCKS - 1) * 256 + threadIdx.x;  // covers N_INC
    int ed = edge_idx[i];
    int nd = node_idx[i];
    int q = nptr[nd] - NOFF + rank_n[i];
    __builtin_nontemporal_store(ed, &ncols[q]);
    return;
  }
  if (blockIdx.x == EAGG_BLOCKS) {
    // ---- scale role: scale = relu(g@W1+b1)@W2 + b2 (threads 0..127) ----
    __shared__ float g[HID], t[HID];
    int c = threadIdx.x;
    if (c < HID) {
      float s = 0.f;
#pragma unroll
      for (int k = 0; k < 8; ++k) s += gsum[k * HID + c];
      g[c] = s * (1.0f / (float)N_NODES);
    }
    __syncthreads();
    if (c < HID) {
      float acc = b1[c];
#pragma unroll 8
      for (int k = 0; k < HID; ++k) acc += g[k] * W1[(size_t)k * HID + c];
      t[c] = fmaxf(acc, 0.f);
    }
    __syncthreads();
    if (c < HID) {
      float acc2 = b2[c];
#pragma unroll 8
      for (int k = 0; k < HID; ++k) acc2 += t[k] * W2[(size_t)k * HID + c];
      scale[c] = acc2;
    }
    return;
  }
  int gw = blockIdx.x * 4 + (threadIdx.x >> 6);
  int lane = threadIdx.x & 63;
  int p0 = eptr[gw], p1 = eptr[gw + 1];
  float ax0 = 0.f, ay0 = 0.f, ax1 = 0.f, ay1 = 0.f;
  float ax2 = 0.f, ay2 = 0.f, ax3 = 0.f, ay3 = 0.f;
  for (int base = p0; base < p1; base += 64) {
    int cnt = min(64, p1 - base);
    int idx = (base + lane < p1) ? ecols[base + lane] : 0;
    int j = 0;
    for (; j + 3 < cnt; j += 4) {
      int n0 = __shfl(idx, j, 64);
      int n1 = __shfl(idx, j + 1, 64);
      int n2 = __shfl(idx, j + 2, 64);
      int n3 = __shfl(idx, j + 3, 64);
      unsigned v0 = *(const unsigned*)(Hb + (size_t)n0 * HID + lane * 2);
      unsigned v1 = *(const unsigned*)(Hb + (size_t)n1 * HID + lane * 2);
      unsigned v2 = *(const unsigned*)(Hb + (size_t)n2 * HID + lane * 2);
      unsigned v3 = *(const unsigned*)(Hb + (size_t)n3 * HID + lane * 2);
      ax0 += __uint_as_float(v0 << 16); ay0 += __uint_as_float(v0 & 0xffff0000u);
      ax1 += __uint_as_float(v1 << 16); ay1 += __uint_as_float(v1 & 0xffff0000u);
      ax2 += __uint_as_float(v2 << 16); ay2 += __uint_as_float(v2 & 0xffff0000u);
      ax3 += __uint_as_float(v3 << 16); ay3 += __uint_as_float(v3 & 0xffff0000u);
    }
    for (; j < cnt; ++j) {
      int n0 = __shfl(idx, j, 64);
      unsigned v0 = *(const unsigned*)(Hb + (size_t)n0 * HID + lane * 2);
      ax0 += __uint_as_float(v0 << 16); ay0 += __uint_as_float(v0 & 0xffff0000u);
    }
  }
  float inv = 1.f / (float)max(p1 - p0, 1);
  float sx = ((ax0 + ax1) + (ax2 + ax3)) * inv;
  float sy = ((ay0 + ay1) + (ay2 + ay3)) * inv;
  unsigned pk = ((unsigned)f32_bf16_rne(sy) << 16) | f32_bf16_rne(sx);
  *(unsigned*)(Eb + (size_t)gw * HID + lane * 2) = pk;
}

// --- node aggregation (bf16 gather) + scale + relu; aux: write Hb + colsum ---
__global__ __launch_bounds__(256) void node_agg_kernel(
    const unsigned short* __restrict__ Eb, const int* __restrict__ nptr,
    const int* __restrict__ ncols, const float* __restrict__ scale,
    unsigned short* __restrict__ Hb, float* __restrict__ H,
    float* __restrict__ gsum, int do_aux)
{
  __shared__ float red[4][HID];
  int wave = threadIdx.x >> 6, lane = threadIdx.x & 63;
  float2 sc = *(const float2*)(scale + lane * 2);
  float csx = 0.f, csy = 0.f;
  for (int gw = blockIdx.x * 4 + wave; gw < N_NODES; gw += NAGG_BLOCKS * 4) {
    int p0 = nptr[gw] - NOFF, p1 = nptr[gw + 1] - NOFF;
    float ax0 = 0.f, ay0 = 0.f, ax1 = 0.f, ay1 = 0.f;
    float ax2 = 0.f, ay2 = 0.f, ax3 = 0.f, ay3 = 0.f;
    for (int base = p0; base < p1; base += 64) {
      int cnt = min(64, p1 - base);
      int idx = (base + lane < p1) ? ncols[base + lane] : 0;
      int j = 0;
      for (; j + 3 < cnt; j += 4) {
        int e0 = __shfl(idx, j, 64);
        int e1 = __shfl(idx, j + 1, 64);
        int e2 = __shfl(idx, j + 2, 64);
        int e3 = __shfl(idx, j + 3, 64);
        unsigned v0 = *(const unsigned*)(Eb + (size_t)e0 * HID + lane * 2);
        unsigned v1 = *(const unsigned*)(Eb + (size_t)e1 * HID + lane * 2);
        unsigned v2 = *(const unsigned*)(Eb + (size_t)e2 * HID + lane * 2);
        unsigned v3 = *(const unsigned*)(Eb + (size_t)e3 * HID + lane * 2);
        ax0 += __uint_as_float(v0 << 16); ay0 += __uint_as_float(v0 & 0xffff0000u);
        ax1 += __uint_as_float(v1 << 16); ay1 += __uint_as_float(v1 & 0xffff0000u);
        ax2 += __uint_as_float(v2 << 16); ay2 += __uint_as_float(v2 & 0xffff0000u);
        ax3 += __uint_as_float(v3 << 16); ay3 += __uint_as_float(v3 & 0xffff0000u);
      }
      for (; j < cnt; ++j) {
        int e0 = __shfl(idx, j, 64);
        unsigned v0 = *(const unsigned*)(Eb + (size_t)e0 * HID + lane * 2);
        ax0 += __uint_as_float(v0 << 16); ay0 += __uint_as_float(v0 & 0xffff0000u);
      }
    }
    float inv = 1.f / (float)max(p1 - p0, 1);
    float ox = fmaxf(((ax0 + ax1) + (ax2 + ax3)) * inv * sc.x, 0.f);
    float oy = fmaxf(((ay0 + ay1) + (ay2 + ay3)) * inv * sc.y, 0.f);
    if (do_aux) {
      unsigned pk = ((unsigned)f32_bf16_rne(oy) << 16) | f32_bf16_rne(ox);
      *(unsigned*)(Hb + (size_t)gw * HID + lane * 2) = pk;
      csx += ox; csy += oy;
    } else {
      *(float2*)(H + (size_t)gw * HID + lane * 2) = make_float2(ox, oy);
    }
  }
  if (do_aux) {
    red[wave][lane * 2] = csx;
    red[wave][lane * 2 + 1] = csy;
    __syncthreads();
    if (threadIdx.x < HID) {
      int c = threadIdx.x;
      float a = red[0][c] + red[1][c] + red[2][c] + red[3][c];
      atomicAdd(&gsum[(blockIdx.x & 7) * HID + c], a);
    }
  }
}

// ---------------- launch ----------------
extern "C" void kernel_launch(void* const* d_in, const int* in_sizes, int n_in,
                              void* d_out, int out_size, void* d_ws, size_t ws_size,
                              hipStream_t stream)
{
  const float* text = (const float*)d_in[0];
  const float* Wp   = (const float*)d_in[1];
  const float* bp   = (const float*)d_in[2];
  const float* W1a  = (const float*)d_in[3];
  const float* b1a  = (const float*)d_in[4];
  const float* W2a  = (const float*)d_in[5];
  const float* b2a  = (const float*)d_in[6];
  const float* W1b  = (const float*)d_in[7];
  const float* b1b  = (const float*)d_in[8];
  const float* W2b  = (const float*)d_in[9];
  const float* b2b  = (const float*)d_in[10];
  const int* node_idx = (const int*)d_in[11];
  const int* edge_idx = (const int*)d_in[12];
  float* H = (float*)d_out;

  // ---- workspace layout (bytes) ----
  char* ws = (char*)d_ws;
  int*      ecp    = (int*)(ws + 0);                       // 20000*EPAD ints
  int*      ncp    = (int*)(ws + 640000);                  // 100000*NPAD ints
  float*    gsum0  = (float*)(ws + 2240000);               // 8*128 floats
  float*    gsum1  = (float*)(ws + 2244096);               // 8*128 floats
  unsigned* status = (unsigned*)(ws + 2248192);            // 118 scan flags (512B pad)
  const size_t zero_bytes = 2248704;
  int*   cptr  = (int*)(ws + 2248704);                     // 120001 ints (eptr||nptr)
  int*   eptr  = cptr;
  int*   nptr  = cptr + N_EDGES;
  int*   ecols = (int*)(ws + 2728712);                     // 800000 ints
  int*   ncols = (int*)(ws + 5928712);                     // 800000 ints
  float* scale0 = (float*)(ws + 9128712);                  // 128
  float* scale1 = (float*)(ws + 9129224);                  // 128
  unsigned short* Eb = (unsigned short*)(ws + 9130000);    // 20000*128 bf16 (5.12 MB)
  unsigned short* Hb = (unsigned short*)(ws + 14250000);   // 100000*128 bf16 -> ends 39.85 MB
  // d_out scratch (fully overwritten by final node_agg): ranks + B tables
  int* rank_e = (int*)d_out;                               // 800000 ints
  int* rank_n = rank_e + N_INC;                            // 800000 ints
  unsigned short* Bh = (unsigned short*)((char*)d_out + 6400000);  // 96 KB
  unsigned short* Bl = (unsigned short*)((char*)d_out + 6498304);  // 96 KB

  hipMemsetAsync(ws, 0, zero_bytes, stream);

  // K0+K1: wprep, then projection ∥ count (count hides under proj, R1-exact)
  wprep_kernel<<<96, 64, 0, stream>>>(Wp, Bh, Bl);
  proj_count_kernel<<<PROJ_BLOCKS + CNT_BLOCKS, 256, 0, stream>>>(
      text, Bh, Bl, bp, Hb, gsum0, node_idx, edge_idx, ecp, ncp, rank_e, rank_n);

  // K2: single-pass lookback scan (120000 -> cptr)
  scan_lookback<<<SCAN_BLOCKS, 1024, 0, stream>>>(ecp, ncp, cptr, status, NKEYS);

  // K3: edge-side fill only (~25us); node-side fill hides under eagg1
  fill_e_kernel<<<FILLE_BLOCKS, 256, 0, stream>>>(
      node_idx, edge_idx, rank_e, eptr, ecols);

  // K4: layer-1 edge agg + scale + fill_n roles
  edge_agg_scale_kernel<<<EAGG_BLOCKS + 1 + FILLN_BLOCKS, 256, 0, stream>>>(
      Hb, eptr, ecols, Eb, gsum0, W1a, b1a, W2a, b2a, scale0,
      node_idx, edge_idx, rank_n, nptr, ncols);
  node_agg_kernel<<<NAGG_BLOCKS, 256, 0, stream>>>(
      Eb, nptr, ncols, scale0, Hb, H, gsum1, 1);

  // layer 2: edge agg (+scale role only), node agg (writes final fp32 H)
  edge_agg_scale_kernel<<<EAGG_BLOCKS + 1, 256, 0, stream>>>(
      Hb, eptr, ecols, Eb, gsum1, W1b, b1b, W2b, b2b, scale1,
      node_idx, edge_idx, rank_n, nptr, ncols);
  node_agg_kernel<<<NAGG_BLOCKS, 256, 0, stream>>>(
      Eb, nptr, ncols, scale1, Hb, H, gsum1, 0);
}